// Round 1
// baseline (6801.485 us; speedup 1.0000x reference)
//
#include <hip/hip_runtime.h>
#include <hip/hip_bf16.h>
#include <math.h>

// B=32, T=256, D=1024, A=64, H=512, NA=20
#define DEV __device__ __forceinline__

typedef __bf16 bf16_t;
typedef bf16_t bf16x8 __attribute__((ext_vector_type(8)));
typedef float f32x4 __attribute__((ext_vector_type(4)));

DEV void async16(const void* g, void* l) {
  __builtin_amdgcn_global_load_lds((const __attribute__((address_space(1))) void*)g,
                                   (__attribute__((address_space(3))) void*)l, 16, 0, 0);
}
DEV float sigmoidf_(float x) { return 1.f / (1.f + expf(-x)); }

// ---------------- generic bf16 MFMA GEMM: C[M,N] = A[M,K] @ Bw[N,K]^T + bias ----------------
// remap==1: output row m -> (m%256)*32 + m/256   (i.e. [B,T] -> [T,B])
__global__ __launch_bounds__(256) void gemm_bt_kernel(
    const __hip_bfloat16* __restrict__ A, const __hip_bfloat16* __restrict__ Bw,
    float* __restrict__ C, const float* __restrict__ bias,
    int M, int N, int K, int remap)
{
  __shared__ __hip_bfloat16 As[128 * 64];
  __shared__ __hip_bfloat16 Bs[128 * 64];
  const int tid = threadIdx.x;
  const int w = tid >> 6, l = tid & 63;
  const int m0 = blockIdx.x * 128, n0 = blockIdx.y * 128;
  const int wm = (w >> 1) * 64, wn = (w & 1) * 64;
  const int row_s = tid >> 3, kc = tid & 7;
  f32x4 acc[4][4] = {};
  for (int k0 = 0; k0 < K; k0 += 64) {
    const __hip_bfloat16* ga = A + (size_t)(m0 + row_s) * K + k0 + kc * 8;
    const __hip_bfloat16* gb = Bw + (size_t)(n0 + row_s) * K + k0 + kc * 8;
    __hip_bfloat16* la = As + w * 512;
    __hip_bfloat16* lb = Bs + w * 512;
#pragma unroll
    for (int p = 0; p < 4; ++p) {
      async16(ga + (size_t)p * 32 * K, la + p * 2048);
      async16(gb + (size_t)p * 32 * K, lb + p * 2048);
    }
    __syncthreads();
#pragma unroll
    for (int kb = 0; kb < 2; ++kb) {
      bf16x8 af[4], bfr[4];
#pragma unroll
      for (int i = 0; i < 4; ++i)
        af[i] = *(const bf16x8*)&As[(wm + i * 16 + (l & 15)) * 64 + kb * 32 + (l >> 4) * 8];
#pragma unroll
      for (int j = 0; j < 4; ++j)
        bfr[j] = *(const bf16x8*)&Bs[(wn + j * 16 + (l & 15)) * 64 + kb * 32 + (l >> 4) * 8];
#pragma unroll
      for (int i = 0; i < 4; ++i)
#pragma unroll
        for (int j = 0; j < 4; ++j)
          acc[i][j] = __builtin_amdgcn_mfma_f32_16x16x32_bf16(af[i], bfr[j], acc[i][j], 0, 0, 0);
    }
    __syncthreads();
  }
#pragma unroll
  for (int i = 0; i < 4; ++i) {
#pragma unroll
    for (int j = 0; j < 4; ++j) {
      const int ncol = n0 + wn + j * 16 + (l & 15);
      const float bv = bias ? bias[ncol] : 0.f;
#pragma unroll
      for (int r = 0; r < 4; ++r) {
        int m = m0 + wm + i * 16 + (l >> 4) * 4 + r;
        int row = remap ? (((m & 255) << 5) | (m >> 8)) : m;
        C[(size_t)row * N + ncol] = acc[i][j][r] + bv;
      }
    }
  }
}

// ---------------- scan step ----------------
struct ScanParams {
  const __hip_bfloat16* hid;     // [T][B][D] bf16
  const float* cell;             // [T][B][D] f32
  const __hip_bfloat16* stackW;  // [4096][2048]  [Whh | Wih]
  const __hip_bfloat16* redW;    // [4096][2048]  (= red_W cast)
  const __hip_bfloat16* actW;    // [4096][1024]  (= act_Whh cast)
  const float* sbias;            // [4096] bih+bhh
  const float* red_b;            // [4096]
  const float* table;            // [20][4096]
  const int* actions;            // [B][T]
  __hip_bfloat16 *sh_bf0, *sh_bf1, *ah_bf0, *ah_bf1, *rh_bf0, *rh_bf1, *bfdummy;
  float *sh_f32, *sc, *ah_f32, *ac, *rc, *s3, *s1, *cdummy;
};

__global__ __launch_bounds__(256) void scan_step_kernel(ScanParams P, int s, int mode)
{
  const int bid = blockIdx.x;
  const int scan = mode ? 0 : (bid >> 6);
  if (!mode && scan == 1 && s >= 255) return;
  const int d0 = (bid & 63) * 16;
  const int tid = threadIdx.x, w = tid >> 6, l = tid & 63;
  __shared__ __hip_bfloat16 As[32 * 64];
  __shared__ __hip_bfloat16 Bs[64 * 64];
  __shared__ float gsm[4][32][16];
  const int p = s & 1;
  const __hip_bfloat16 *hsrc, *xsrc, *W;
  int KT, Kw;
  const float* c_read; float* c_write; float* hf_out; __hip_bfloat16* hbf_out;
  if (mode) {
    hsrc = P.sh_bf0; xsrc = P.rh_bf1; W = P.stackW; KT = 32; Kw = 2048;
    c_read = P.sc; c_write = P.cdummy; hf_out = P.s1; hbf_out = P.bfdummy;
  } else if (scan == 0) {
    hsrc = p ? P.sh_bf1 : P.sh_bf0; xsrc = P.hid + (size_t)s * 32768;
    W = P.stackW; KT = 32; Kw = 2048;
    c_read = P.sc; c_write = P.sc; hf_out = P.sh_f32;
    hbf_out = p ? P.sh_bf0 : P.sh_bf1;
  } else if (scan == 1) {
    hsrc = p ? P.rh_bf1 : P.rh_bf0; xsrc = P.hid + (size_t)(s + 1) * 32768;
    W = P.redW; KT = 32; Kw = 2048;
    c_read = P.rc; c_write = P.rc; hf_out = nullptr;
    hbf_out = p ? P.rh_bf0 : P.rh_bf1;
  } else {
    hsrc = p ? P.ah_bf1 : P.ah_bf0; xsrc = nullptr;
    W = P.actW; KT = 16; Kw = 1024;
    c_read = P.ac; c_write = P.ac; hf_out = P.ah_f32;
    hbf_out = p ? P.ah_bf0 : P.ah_bf1;
  }
  const int row_s = tid >> 3, kc = tid & 7;
  f32x4 acc0 = {}, acc1 = {};
  for (int kt = 0; kt < KT; ++kt) {
    const int k0 = kt * 64;
    const __hip_bfloat16* asrc = (k0 < 1024) ? (hsrc + k0) : (xsrc + (k0 - 1024));
    async16(asrc + row_s * 1024 + kc * 8, As + w * 512);
#pragma unroll
    for (int q = 0; q < 2; ++q) {
      int r = q * 32 + row_s;
      int wrow = (r >> 4) * 1024 + d0 + (r & 15);
      async16(W + (size_t)wrow * Kw + k0 + kc * 8, Bs + q * 2048 + w * 512);
    }
    __syncthreads();
#pragma unroll
    for (int kb = 0; kb < 2; ++kb) {
      bf16x8 a0 = *(const bf16x8*)&As[(l & 15) * 64 + kb * 32 + (l >> 4) * 8];
      bf16x8 a1 = *(const bf16x8*)&As[((l & 15) + 16) * 64 + kb * 32 + (l >> 4) * 8];
      bf16x8 b0 = *(const bf16x8*)&Bs[(w * 16 + (l & 15)) * 64 + kb * 32 + (l >> 4) * 8];
      acc0 = __builtin_amdgcn_mfma_f32_16x16x32_bf16(a0, b0, acc0, 0, 0, 0);
      acc1 = __builtin_amdgcn_mfma_f32_16x16x32_bf16(a1, b0, acc1, 0, 0, 0);
    }
    __syncthreads();
  }
#pragma unroll
  for (int i = 0; i < 4; ++i) {
    gsm[w][(l >> 4) * 4 + i][l & 15] = acc0[i];
    gsm[w][16 + (l >> 4) * 4 + i][l & 15] = acc1[i];
  }
  __syncthreads();
  for (int e = tid; e < 512; e += 256) {
    const int b = e >> 4, dd = e & 15, d = d0 + dd;
    const int sidx = b * 1024 + d;
    float g0 = gsm[0][b][dd], g1 = gsm[1][b][dd], g2 = gsm[2][b][dd], g3 = gsm[3][b][dd];
    if (scan == 1) {
      float ig = sigmoidf_(g0 + P.red_b[d]);
      float lg = sigmoidf_(g1 + P.red_b[1024 + d]);
      float rg = sigmoidf_(g2 + P.red_b[2048 + d]);
      float cand = tanhf(g3 + P.red_b[3072 + d]);
      float lc = P.rc[sidx];
      float rcv = P.cell[(size_t)(s + 1) * 32768 + sidx];
      float c2 = ig * cand + lg * lc + rg * rcv;
      P.rc[sidx] = c2;
      hbf_out[sidx] = __float2bfloat16(tanhf(c2));
    } else {
      float bi0, bi1, bi2, bi3;
      if (scan == 2) {
        int a = P.actions[b * 256 + s];
        const float* tb = P.table + a * 4096;
        bi0 = tb[d]; bi1 = tb[1024 + d]; bi2 = tb[2048 + d]; bi3 = tb[3072 + d];
      } else {
        bi0 = P.sbias[d]; bi1 = P.sbias[1024 + d]; bi2 = P.sbias[2048 + d]; bi3 = P.sbias[3072 + d];
      }
      float c = c_read[sidx];
      float c2 = sigmoidf_(g1 + bi1) * c + sigmoidf_(g0 + bi0) * tanhf(g2 + bi2);
      float h2 = sigmoidf_(g3 + bi3) * tanhf(c2);
      c_write[sidx] = c2;
      if (hf_out) hf_out[sidx] = h2;
      hbf_out[sidx] = __float2bfloat16(h2);
      if (scan == 0 && mode == 0 && s == 254) P.s3[sidx] = h2;
    }
  }
}

// ---------------- small utility kernels ----------------
__global__ void cast_kernel(__hip_bfloat16* dst, const float* src, int n) {
  int i = blockIdx.x * 256 + threadIdx.x;
  if (i < n) dst[i] = __float2bfloat16(src[i]);
}
__global__ void cast_strided_kernel(__hip_bfloat16* dst, const float* src, int n, int dst_stride) {
  int i = blockIdx.x * 256 + threadIdx.x;
  if (i < n) {
    int r = i >> 10, c = i & 1023;
    dst[(size_t)r * dst_stride + c] = __float2bfloat16(src[i]);
  }
}
__global__ void bias_kernel(float* dst, const float* a, const float* b, int n) {
  int i = blockIdx.x * 256 + threadIdx.x;
  if (i < n) dst[i] = a[i] + b[i];
}
__global__ void leaf_elem_kernel(const float* cellf, const float* hidpre, __hip_bfloat16* hid_bf, int n) {
  int i = blockIdx.x * 256 + threadIdx.x;
  if (i < n) {
    float c = cellf[i];
    float hp = hidpre[i];
    hid_bf[i] = __float2bfloat16(sigmoidf_(hp) * tanhf(c));
  }
}
__global__ void act_table_kernel(const float* emb, const float* Wih, const float* bih,
                                 const float* bhh, float* table) {
  int i = blockIdx.x * 256 + threadIdx.x;  // 20*4096
  int a = i >> 12, n = i & 4095;
  float acc = bih[n] + bhh[n];
  const float* er = emb + a * 64;
  const float* wr = Wih + (size_t)n * 64;
  for (int k = 0; k < 64; ++k) acc += er[k] * wr[k];
  table[i] = acc;
}
__global__ void init_states_kernel(
    const float* stack_h0, const float* stack_c0, const float* act_h0, const float* act_c0,
    const __hip_bfloat16* hid, const float* cell,
    __hip_bfloat16* sh_bf0, float* sh_f32, float* sc,
    __hip_bfloat16* ah_bf0, float* ah_f32, float* ac,
    __hip_bfloat16* rh_bf0, float* rc)
{
  int i = blockIdx.x * 256 + threadIdx.x;  // 32768
  int d = i & 1023;
  sh_bf0[i] = __float2bfloat16(stack_h0[d]);
  sh_f32[i] = stack_h0[d];
  sc[i] = stack_c0[d];
  ah_bf0[i] = __float2bfloat16(act_h0[d]);
  ah_f32[i] = act_h0[d];
  ac[i] = act_c0[d];
  rh_bf0[i] = hid[i];
  rc[i] = cell[i];
}

// ---------------- attention ----------------
__global__ __launch_bounds__(256) void att_q_kernel(
    const float* s1, const float* s2, const float* s3, const float* attW, float* q)
{
  int eb = blockIdx.x, bg = blockIdx.y, j = blockIdx.z;
  const float* sj = (j == 0) ? s1 : ((j == 1) ? s2 : s3);
  __shared__ float ls[4][1024];
  int tid = threadIdx.x;
  for (int i = tid; i < 4096; i += 256)
    ls[i >> 10][i & 1023] = sj[(size_t)(bg * 4 + (i >> 10)) * 1024 + (i & 1023)];
  __syncthreads();
  int e = eb * 256 + tid;
  const float* Wj = attW + (size_t)j * 1024 * 1024;
  float a0 = 0, a1 = 0, a2 = 0, a3 = 0;
  for (int d = 0; d < 1024; ++d) {
    float wv = Wj[(size_t)d * 1024 + e];
    a0 += ls[0][d] * wv; a1 += ls[1][d] * wv; a2 += ls[2][d] * wv; a3 += ls[3][d] * wv;
  }
  q[((size_t)j * 32 + bg * 4 + 0) * 1024 + e] = a0;
  q[((size_t)j * 32 + bg * 4 + 1) * 1024 + e] = a1;
  q[((size_t)j * 32 + bg * 4 + 2) * 1024 + e] = a2;
  q[((size_t)j * 32 + bg * 4 + 3) * 1024 + e] = a3;
}

__global__ __launch_bounds__(256) void att_sc_kernel(const float* q, const float* sent, float* att)
{
  int b = blockIdx.x, j = blockIdx.y;
  __shared__ float qs[1024];
  __shared__ float wsm[256];
  __shared__ float red[8];
  int tid = threadIdx.x, w = tid >> 6, l = tid & 63;
  for (int i = tid; i < 1024; i += 256) qs[i] = q[((size_t)j * 32 + b) * 1024 + i];
  __syncthreads();
  const float* sp = sent + ((size_t)b * 256 + tid) * 1024;
  float dot = 0;
  for (int k = 0; k < 1024; ++k) dot += qs[k] * sp[k];
  float v = dot;
  for (int off = 32; off; off >>= 1) v = fmaxf(v, __shfl_xor(v, off));
  if (l == 0) red[w] = v;
  __syncthreads();
  float m = fmaxf(fmaxf(red[0], red[1]), fmaxf(red[2], red[3]));
  float ex = expf(dot - m);
  float sv = ex;
  for (int off = 32; off; off >>= 1) sv += __shfl_xor(sv, off);
  if (l == 0) red[4 + w] = sv;
  __syncthreads();
  float ssum = red[4] + red[5] + red[6] + red[7];
  wsm[tid] = ex / ssum;
  __syncthreads();
  for (int it = 0; it < 4; ++it) {
    int e = it * 256 + tid;
    float a = 0;
    for (int t2 = 0; t2 < 256; ++t2) a += wsm[t2] * sent[((size_t)b * 256 + t2) * 1024 + e];
    att[((size_t)j * 32 + b) * 1024 + e] = a;
  }
}

// ---------------- head ----------------
__global__ void feat_kernel(const float* s1, const float* s2, const float* s3,
                            const float* tok, const float* atop, const float* att, float* feat)
{
  int i = blockIdx.x * 256 + threadIdx.x;  // 32*8192
  int b = i >> 13, jj = (i >> 10) & 7, d = i & 1023;
  int sidx = b * 1024 + d;
  float v;
  switch (jj) {
    case 0: v = s1[sidx]; break;
    case 1: v = s2[sidx]; break;
    case 2: v = s3[sidx]; break;
    case 3: v = tok[d]; break;
    case 4: v = atop[sidx]; break;
    default: v = att[((size_t)(jj - 5) * 32 + b) * 1024 + d];
  }
  feat[i] = v;
}
__global__ __launch_bounds__(256) void head_kernel(const float* feat, const float* W,
                                                   const float* bias, float* fbuf)
{
  int i = blockIdx.x * 256 + threadIdx.x;  // 32*512
  int b = i >> 9, h = i & 511;
  const float* fr = feat + (size_t)b * 8192;
  const float* wr = W + (size_t)h * 8192;
  float a = bias[h];
  for (int k = 0; k < 8192; ++k) a += fr[k] * wr[k];
  fbuf[i] = tanhf(a);
}
__global__ void logits_kernel(const float* fbuf, const float* W, const float* bias, float* out)
{
  int b = blockIdx.x, tid = threadIdx.x;  // block 64
  __shared__ float lg[20];
  __shared__ float mred, lsred;
  if (tid < 20) {
    const float* fr = fbuf + b * 512;
    const float* wr = W + tid * 512;
    float a = bias[tid];
    for (int k = 0; k < 512; ++k) a += fr[k] * wr[k];
    lg[tid] = a;
  }
  __syncthreads();
  if (tid == 0) {
    float m = lg[0];
    for (int i = 1; i < 20; ++i) m = fmaxf(m, lg[i]);
    float ssum = 0;
    for (int i = 0; i < 20; ++i) ssum += expf(lg[i] - m);
    mred = m; lsred = logf(ssum);
  }
  __syncthreads();
  if (tid < 20) out[b * 20 + tid] = lg[tid] - mred - lsred;
}

// ---------------- host ----------------
extern "C" void kernel_launch(void* const* d_in, const int* in_sizes, int n_in,
                              void* d_out, int out_size, void* d_ws, size_t ws_size,
                              hipStream_t stream)
{
  const float* sentence = (const float*)d_in[0];
  const int* actions = (const int*)d_in[1];
  const float* token_empty = (const float*)d_in[2];
  const float* leaf_Wi = (const float*)d_in[3];
  const float* leaf_bi = (const float*)d_in[4];
  const float* leaf_Wo = (const float*)d_in[5];
  const float* leaf_bo = (const float*)d_in[6];
  const float* lstm_Wih = (const float*)d_in[7];
  const float* lstm_Whh = (const float*)d_in[8];
  const float* lstm_bih = (const float*)d_in[9];
  const float* lstm_bhh = (const float*)d_in[10];
  const float* stack_h0 = (const float*)d_in[11];
  const float* stack_c0 = (const float*)d_in[12];
  const float* act_emb = (const float*)d_in[13];
  const float* act_Wih = (const float*)d_in[14];
  const float* act_Whh = (const float*)d_in[15];
  const float* act_bih = (const float*)d_in[16];
  const float* act_bhh = (const float*)d_in[17];
  const float* act_h0 = (const float*)d_in[18];
  const float* act_c0 = (const float*)d_in[19];
  const float* red_W = (const float*)d_in[20];
  const float* red_b = (const float*)d_in[21];
  const float* h2f_W = (const float*)d_in[22];
  const float* h2f_b = (const float*)d_in[23];
  const float* f2a_W = (const float*)d_in[24];
  const float* f2a_b = (const float*)d_in[25];
  const float* att_W = (const float*)d_in[26];
  float* out = (float*)d_out;

  char* ws = (char*)d_ws;
  size_t off = 0;
  auto alloc = [&](size_t bytes) -> void* {
    void* ptr = ws + off;
    off += (bytes + 255) & ~(size_t)255;
    return ptr;
  };
  __hip_bfloat16* sent_bf = (__hip_bfloat16*)alloc(16777216);
  __hip_bfloat16* hid_bf  = (__hip_bfloat16*)alloc(16777216);
  float* cell_f32 = (float*)alloc(33554432);
  float* hidpre   = (float*)alloc(33554432);
  __hip_bfloat16* lWi_bf = (__hip_bfloat16*)alloc(2097152);
  __hip_bfloat16* lWo_bf = (__hip_bfloat16*)alloc(2097152);
  __hip_bfloat16* stackW = (__hip_bfloat16*)alloc(16777216);
  __hip_bfloat16* redWb  = (__hip_bfloat16*)alloc(16777216);
  __hip_bfloat16* actWb  = (__hip_bfloat16*)alloc(8388608);
  float* table = (float*)alloc(327680);
  float* sbias = (float*)alloc(16384);
  __hip_bfloat16* sh_bf0 = (__hip_bfloat16*)alloc(65536);
  __hip_bfloat16* sh_bf1 = (__hip_bfloat16*)alloc(65536);
  __hip_bfloat16* ah_bf0 = (__hip_bfloat16*)alloc(65536);
  __hip_bfloat16* ah_bf1 = (__hip_bfloat16*)alloc(65536);
  __hip_bfloat16* rh_bf0 = (__hip_bfloat16*)alloc(65536);
  __hip_bfloat16* rh_bf1 = (__hip_bfloat16*)alloc(65536);
  __hip_bfloat16* bfdummy = (__hip_bfloat16*)alloc(65536);
  float* sh_f32 = (float*)alloc(131072);
  float* sc = (float*)alloc(131072);
  float* ah_f32 = (float*)alloc(131072);
  float* ac = (float*)alloc(131072);
  float* rc = (float*)alloc(131072);
  float* s3 = (float*)alloc(131072);
  float* s1 = (float*)alloc(131072);
  float* cdummy = (float*)alloc(131072);
  float* qbuf = (float*)alloc(393216);
  float* attbuf = (float*)alloc(393216);
  float* feat = (float*)alloc(1048576);
  float* fbuf = (float*)alloc(65536);
  (void)ws_size; (void)in_sizes; (void)n_in; (void)out_size;

  // weight / input conversions
  cast_kernel<<<32768, 256, 0, stream>>>(sent_bf, sentence, 8388608);
  cast_kernel<<<4096, 256, 0, stream>>>(lWi_bf, leaf_Wi, 1048576);
  cast_kernel<<<4096, 256, 0, stream>>>(lWo_bf, leaf_Wo, 1048576);
  cast_strided_kernel<<<16384, 256, 0, stream>>>(stackW, lstm_Whh, 4194304, 2048);
  cast_strided_kernel<<<16384, 256, 0, stream>>>(stackW + 1024, lstm_Wih, 4194304, 2048);
  cast_kernel<<<32768, 256, 0, stream>>>(redWb, red_W, 8388608);
  cast_kernel<<<16384, 256, 0, stream>>>(actWb, act_Whh, 4194304);
  bias_kernel<<<16, 256, 0, stream>>>(sbias, lstm_bih, lstm_bhh, 4096);
  act_table_kernel<<<320, 256, 0, stream>>>(act_emb, act_Wih, act_bih, act_bhh, table);

  // leaf module
  gemm_bt_kernel<<<dim3(64, 8), 256, 0, stream>>>(sent_bf, lWi_bf, cell_f32, leaf_bi,
                                                  8192, 1024, 1024, 1);
  gemm_bt_kernel<<<dim3(64, 8), 256, 0, stream>>>(sent_bf, lWo_bf, hidpre, leaf_bo,
                                                  8192, 1024, 1024, 1);
  leaf_elem_kernel<<<32768, 256, 0, stream>>>(cell_f32, hidpre, hid_bf, 8388608);

  // init scan states
  init_states_kernel<<<128, 256, 0, stream>>>(stack_h0, stack_c0, act_h0, act_c0,
                                              hid_bf, cell_f32,
                                              sh_bf0, sh_f32, sc,
                                              ah_bf0, ah_f32, ac,
                                              rh_bf0, rc);

  ScanParams P;
  P.hid = hid_bf; P.cell = cell_f32;
  P.stackW = stackW; P.redW = redWb; P.actW = actWb;
  P.sbias = sbias; P.red_b = red_b; P.table = table; P.actions = actions;
  P.sh_bf0 = sh_bf0; P.sh_bf1 = sh_bf1;
  P.ah_bf0 = ah_bf0; P.ah_bf1 = ah_bf1;
  P.rh_bf0 = rh_bf0; P.rh_bf1 = rh_bf1;
  P.bfdummy = bfdummy;
  P.sh_f32 = sh_f32; P.sc = sc;
  P.ah_f32 = ah_f32; P.ac = ac;
  P.rc = rc; P.s3 = s3; P.s1 = s1; P.cdummy = cdummy;

  for (int s = 0; s < 256; ++s)
    scan_step_kernel<<<192, 256, 0, stream>>>(P, s, 0);
  // s1 = lstm_cell(red_h, hf, cf)
  scan_step_kernel<<<64, 256, 0, stream>>>(P, 0, 1);

  // attention: s1, s2 (=sh_f32), s3
  att_q_kernel<<<dim3(4, 8, 3), 256, 0, stream>>>(s1, sh_f32, s3, att_W, qbuf);
  att_sc_kernel<<<dim3(32, 3), 256, 0, stream>>>(qbuf, sentence, attbuf);

  // head
  feat_kernel<<<1024, 256, 0, stream>>>(s1, sh_f32, s3, token_empty, ah_f32, attbuf, feat);
  head_kernel<<<64, 256, 0, stream>>>(feat, h2f_W, h2f_b, fbuf);
  logits_kernel<<<32, 64, 0, stream>>>(fbuf, f2a_W, f2a_b, out);
}